// Round 5
// baseline (1253.671 us; speedup 1.0000x reference)
//
#include <hip/hip_runtime.h>
#include <hip/hip_bf16.h>

#define NN 100000
#define NE 1600000

typedef __hip_bfloat16 bf16;
typedef unsigned short u16;
typedef short bshort8 __attribute__((ext_vector_type(8)));
typedef float f32x4 __attribute__((ext_vector_type(4)));

__device__ __forceinline__ float b2f_raw(u16 u) {
    unsigned int w = ((unsigned int)u) << 16;
    float f; __builtin_memcpy(&f, &w, 4); return f;
}
__device__ __forceinline__ u16 f2bu(float f) {
    bf16 h = __float2bfloat16(f); u16 u; __builtin_memcpy(&u, &h, 2); return u;
}
__device__ __forceinline__ float eluf(float x) { return x > 0.f ? x : expm1f(x); }
__device__ __forceinline__ bshort8 u4_to_s8(uint4 v) {
    union { uint4 u; bshort8 s; } x; x.u = v; return x.s;
}

// canonical weight block offsets (f32 words)
#define OFF_ENC_W0 0
#define OFF_ENC_B0 192
#define OFF_ENC_W1 256
#define OFF_ENC_B1 4352
#define OFF_DEC_W0 4416
#define OFF_DEC_B0 8512
#define OFF_DEC_W1 8576
#define OFF_DEC_B1 8768
#define OFF_EW0    8832     // raw [2,195,64]
#define OFF_EB0    33792
#define OFF_EW1    33920
#define OFF_EB1    42112
#define OFF_NW0    42240
#define OFF_NB0    58624
#define OFF_NW1    58752
#define OFF_NB1    66944
#define OFF_CA     67072
#define OFF_CB     75264
#define WBLK_WORDS 83456

__global__ void probe_kernel(const u16* __restrict__ xr,
                             const unsigned int* __restrict__ er,
                             int* __restrict__ flags) {
    if (blockIdx.x == 0 && threadIdx.x == 0) {
        int wild = 0;
        for (int j = 0; j < 256; ++j) {
            int e = (xr[j] >> 7) & 0xFF;
            if (e > 140 || (e < 90 && e != 0)) wild++;
        }
        flags[0] = (wild > 16) ? 1 : 0;
        int oddnz = 0;
        for (int j = 1; j < 256; j += 2) if (er[j] != 0u) oddnz++;
        flags[1] = (oddnz < 8) ? 1 : 0;
    }
}

struct WPtrs { const void* p[16]; };

__global__ void canon_weights(WPtrs wp, float* __restrict__ wblk,
                              const int* __restrict__ flags) {
    const int offs[16] = {OFF_ENC_W0, OFF_ENC_B0, OFF_ENC_W1, OFF_ENC_B1,
                          OFF_DEC_W0, OFF_DEC_B0, OFF_DEC_W1, OFF_DEC_B1,
                          OFF_EW0, OFF_EB0, OFF_EW1, OFF_EB1,
                          OFF_NW0, OFF_NB0, OFF_NW1, OFF_NB1};
    const int ns[16]   = {192, 64, 4096, 64, 4096, 64, 192, 3,
                          24960, 128, 8192, 128, 16384, 128, 8192, 128};
    int t = blockIdx.y;
    int i = blockIdx.x * blockDim.x + threadIdx.x;
    if (i >= ns[t]) return;
    const void* s = wp.p[t];
    float v = flags[0] ? ((const float*)s)[i] : b2f_raw(((const u16*)s)[i]);
    wblk[offs[t] + i] = v;
}

__global__ void canon_xp(const void* __restrict__ xsrc, const void* __restrict__ psrc,
                         float* __restrict__ xf, float* __restrict__ pf,
                         const int* __restrict__ flags) {
    int i = blockIdx.x * 256 + threadIdx.x;
    if (i >= NN * 3) return;
    const void* s = blockIdx.y ? psrc : xsrc;
    float* d = blockIdx.y ? pf : xf;
    d[i] = flags[0] ? ((const float*)s)[i] : b2f_raw(((const u16*)s)[i]);
}

// pack clamped (src,dst) pairs once: one coalesced 8B load in the hot loop
__global__ void prep_edges(const void* __restrict__ eiraw,
                           int2* __restrict__ epk, const int* __restrict__ flags) {
    int e = blockIdx.x * 256 + threadIdx.x;
    if (e >= NE) return;
    int s, d;
    if (flags[1]) {
        s = (int)((const long long*)eiraw)[e];
        d = (int)((const long long*)eiraw)[(size_t)NE + e];
    } else {
        s = ((const int*)eiraw)[e];
        d = ((const int*)eiraw)[(size_t)NE + e];
    }
    if ((unsigned)s >= NN) s = 0;
    if ((unsigned)d >= NN) d = 0;
    epk[e] = make_int2(s, d);
}

// fold layer-1 edge weights: xn*Wa + xo*Wb + (xn-xo)*Wc = xn*(Wa+Wc) + xo*(Wb-Wc)
__global__ void prep_cacb(float* __restrict__ wblk) {
    int idx = blockIdx.x * 256 + threadIdx.x;
    if (idx >= 8192) return;
    int l = idx >> 12, r = idx & 4095, k = r >> 6, c = r & 63;
    const float* W = wblk + OFF_EW0 + l * 12480;
    float wa = W[k * 64 + c], wb = W[(64 + k) * 64 + c], wc = W[(128 + k) * 64 + c];
    wblk[OFF_CA + idx] = wa + wc;
    wblk[OFF_CB + idx] = wb - wc;
}

// Pre-swizzle edge-MLP weights into MFMA B-fragment order (bf16).
__global__ void prep_swz(const float* __restrict__ wblk, u16* __restrict__ swz) {
    int t = blockIdx.x * 256 + threadIdx.x;
    if (t < 20480) {
        int l = t / 10240, r = t % 10240;
        int ks = r >> 11, lane = (r >> 3) & 63, j = r & 7;
        int nt = (r >> 9) & 3;
        int k = ks * 32 + (lane >> 4) * 8 + j;
        int n = nt * 16 + (lane & 15);
        float v = 0.f;
        if (k < 64)       v = wblk[OFF_CA + l * 4096 + k * 64 + n];
        else if (k < 128) v = wblk[OFF_CB + l * 4096 + (k - 64) * 64 + n];
        else if (k < 131) v = wblk[OFF_EW0 + l * 12480 + (192 + (k - 128)) * 64 + n];
        swz[l * 10240 + r] = f2bu(v);
    } else if (t < 20480 + 8192) {
        int t2 = t - 20480;
        int l = t2 / 4096, r = t2 % 4096;
        int ks = r >> 11, lane = (r >> 3) & 63, j = r & 7;
        int nt = (r >> 9) & 3;
        int k = ks * 32 + (lane >> 4) * 8 + j;
        int n = nt * 16 + (lane & 15);
        swz[20480 + l * 4096 + r] = f2bu(wblk[OFF_EW1 + l * 4096 + k * 64 + n]);
    }
}

__global__ void zero_agg(float* __restrict__ agg) {
    int i = blockIdx.x * 256 + threadIdx.x;
    if (i < NN * 16) ((float4*)agg)[i] = make_float4(0.f, 0.f, 0.f, 0.f);
}

__global__ void encoder_kernel(const float* __restrict__ xf,
                               const float* __restrict__ wblk,
                               float* __restrict__ h, u16* __restrict__ h2) {
    __shared__ __attribute__((aligned(16))) float t[4][64];
    int ty = threadIdx.y, c = threadIdx.x;
    int n = blockIdx.x * 4 + ty;
    const float* W0 = wblk + OFF_ENC_W0;
    const float* b0 = wblk + OFF_ENC_B0;
    const float* W1 = wblk + OFF_ENC_W1;
    const float* b1 = wblk + OFF_ENC_B1;
    float acc = b0[c] + xf[n * 3 + 0] * W0[c] + xf[n * 3 + 1] * W0[64 + c]
                      + xf[n * 3 + 2] * W0[128 + c];
    acc = eluf(acc);
    t[ty][c] = acc;
    __syncthreads();
    float a2 = b1[c];
#pragma unroll
    for (int k = 0; k < 64; ++k) a2 += t[ty][k] * W1[k * 64 + c];
    h[(size_t)n * 64 + c] = a2;
    h2[(size_t)n * 64 + c] = f2bu(a2);
}

// MFMA edge kernel, 2-deep software pipeline:
//   iter g: issue h-row loads for g+1 (indices already resident), issue index
//   load for g+2, then compute group g (28 MFMAs + ELU + LDS transpose + atomics).
__global__ __launch_bounds__(256) void edge_mfma(
    const u16* __restrict__ h2, const float* __restrict__ pf,
    const int2* __restrict__ epk,
    const u16* __restrict__ swB1, const u16* __restrict__ swB2,
    const float* __restrict__ eb0p, const float* __restrict__ eb1p,
    float* __restrict__ agg, int ngroups, int nwaves) {
    __shared__ __attribute__((aligned(16))) u16 sB1[10240];
    __shared__ __attribute__((aligned(16))) u16 sB2[4096];
    __shared__ __attribute__((aligned(16))) u16 sP[4][16 * 72];
    int tid = threadIdx.x;
    for (int i = tid; i < 1280; i += 256) ((uint4*)sB1)[i] = ((const uint4*)swB1)[i];
    for (int i = tid; i < 512; i += 256)  ((uint4*)sB2)[i] = ((const uint4*)swB2)[i];
    __syncthreads();
    int wid = tid >> 6, l = tid & 63;
    int m16 = l & 15, half = l >> 4;
    float bias1[4], bias2[4];
#pragma unroll
    for (int nt = 0; nt < 4; ++nt) {
        bias1[nt] = eb0p[nt * 16 + m16];
        bias2[nt] = eb1p[nt * 16 + m16];
    }
    u16* myP = sP[wid];
    const bshort8* B1 = (const bshort8*)sB1;
    const bshort8* B2 = (const bshort8*)sB2;

    int g0 = blockIdx.x * 4 + wid;
    // pipeline state
    int2 ecur, enxt;
    uint4 rc0, rc1, rc2, rc3;
    float pdc0 = 0.f, pdc1 = 0.f, pdc2 = 0.f;
    {
        int ga = (g0 < ngroups) ? g0 : (ngroups - 1);
        ecur = epk[(size_t)ga * 16 + m16];
        const uint4* rs = (const uint4*)(h2 + (size_t)ecur.x * 64);
        const uint4* rd = (const uint4*)(h2 + (size_t)ecur.y * 64);
        rc0 = rs[half]; rc1 = rs[half + 4]; rc2 = rd[half]; rc3 = rd[half + 4];
        if (half == 0) {
            pdc0 = pf[ecur.x * 3 + 0] - pf[ecur.y * 3 + 0];
            pdc1 = pf[ecur.x * 3 + 1] - pf[ecur.y * 3 + 1];
            pdc2 = pf[ecur.x * 3 + 2] - pf[ecur.y * 3 + 2];
        }
        int gb = (g0 + nwaves < ngroups) ? (g0 + nwaves) : (ngroups - 1);
        enxt = epk[(size_t)gb * 16 + m16];
    }

    for (int g = g0; g < ngroups; g += nwaves) {
        // ---- prefetch stage: rows for g+1 (from enxt), indices for g+2 ----
        uint4 rn0, rn1, rn2, rn3;
        float pdn0 = 0.f, pdn1 = 0.f, pdn2 = 0.f;
        int2 efut;
        {
            const uint4* rs = (const uint4*)(h2 + (size_t)enxt.x * 64);
            const uint4* rd = (const uint4*)(h2 + (size_t)enxt.y * 64);
            rn0 = rs[half]; rn1 = rs[half + 4]; rn2 = rd[half]; rn3 = rd[half + 4];
            if (half == 0) {
                pdn0 = pf[enxt.x * 3 + 0] - pf[enxt.y * 3 + 0];
                pdn1 = pf[enxt.x * 3 + 1] - pf[enxt.y * 3 + 1];
                pdn2 = pf[enxt.x * 3 + 2] - pf[enxt.y * 3 + 2];
            }
            int gf = g + 2 * nwaves;
            gf = (gf < ngroups) ? gf : (ngroups - 1);
            efut = epk[(size_t)gf * 16 + m16];
        }

        // ---- compute group g ----
        uint4 a4 = make_uint4(0, 0, 0, 0);
        if (half == 0) {
            a4.x = (unsigned)f2bu(pdc0) | ((unsigned)f2bu(pdc1) << 16);
            a4.y = (unsigned)f2bu(pdc2);
        }
        f32x4 acc[4];
#pragma unroll
        for (int nt = 0; nt < 4; ++nt)
            acc[nt] = f32x4{bias1[nt], bias1[nt], bias1[nt], bias1[nt]};
        {
            bshort8 av0 = u4_to_s8(rc0), av1 = u4_to_s8(rc1);
            bshort8 av2 = u4_to_s8(rc2), av3 = u4_to_s8(rc3);
            bshort8 av4 = u4_to_s8(a4);
#pragma unroll
            for (int nt = 0; nt < 4; ++nt)
                acc[nt] = __builtin_amdgcn_mfma_f32_16x16x32_bf16(av0, B1[nt * 64 + l], acc[nt], 0, 0, 0);
#pragma unroll
            for (int nt = 0; nt < 4; ++nt)
                acc[nt] = __builtin_amdgcn_mfma_f32_16x16x32_bf16(av1, B1[(4 + nt) * 64 + l], acc[nt], 0, 0, 0);
#pragma unroll
            for (int nt = 0; nt < 4; ++nt)
                acc[nt] = __builtin_amdgcn_mfma_f32_16x16x32_bf16(av2, B1[(8 + nt) * 64 + l], acc[nt], 0, 0, 0);
#pragma unroll
            for (int nt = 0; nt < 4; ++nt)
                acc[nt] = __builtin_amdgcn_mfma_f32_16x16x32_bf16(av3, B1[(12 + nt) * 64 + l], acc[nt], 0, 0, 0);
#pragma unroll
            for (int nt = 0; nt < 4; ++nt)
                acc[nt] = __builtin_amdgcn_mfma_f32_16x16x32_bf16(av4, B1[(16 + nt) * 64 + l], acc[nt], 0, 0, 0);
        }
        // ELU + transpose to A-layout via per-wave LDS (in-order, no barrier)
#pragma unroll
        for (int nt = 0; nt < 4; ++nt) {
#pragma unroll
            for (int r = 0; r < 4; ++r) {
                float v = acc[nt][r];
                v = v > 0.f ? v : expm1f(v);
                myP[(half * 4 + r) * 72 + nt * 16 + m16] = f2bu(v);
            }
        }
        f32x4 acc2[4];
#pragma unroll
        for (int nt = 0; nt < 4; ++nt)
            acc2[nt] = f32x4{bias2[nt], bias2[nt], bias2[nt], bias2[nt]};
#pragma unroll
        for (int ks = 0; ks < 2; ++ks) {
            bshort8 av = *(const bshort8*)(myP + m16 * 72 + ks * 32 + half * 8);
#pragma unroll
            for (int nt = 0; nt < 4; ++nt)
                acc2[nt] = __builtin_amdgcn_mfma_f32_16x16x32_bf16(
                    av, B2[(ks * 4 + nt) * 64 + l], acc2[nt], 0, 0, 0);
        }
        int dstm = ecur.y;
        int dstr[4];
#pragma unroll
        for (int r = 0; r < 4; ++r) dstr[r] = __shfl(dstm, half * 4 + r);
#pragma unroll
        for (int nt = 0; nt < 4; ++nt)
#pragma unroll
            for (int r = 0; r < 4; ++r)
                atomicAdd(&agg[(size_t)dstr[r] * 64 + nt * 16 + m16], acc2[nt][r]);

        // ---- shift pipeline ----
        ecur = enxt; enxt = efut;
        rc0 = rn0; rc1 = rn1; rc2 = rn2; rc3 = rn3;
        pdc0 = pdn0; pdc1 = pdn1; pdc2 = pdn2;
    }
}

// node MLP + residual; on the last layer the decoder is fused in and h/h2
// writes are skipped (h is dead after the decoder).
__global__ void node_kernel(float* __restrict__ h, u16* __restrict__ h2,
                            const float* __restrict__ agg,
                            const float* __restrict__ wblk, int l, int last,
                            void* __restrict__ out, const int* __restrict__ flags) {
    __shared__ __attribute__((aligned(16))) float hn[4][64];
    __shared__ __attribute__((aligned(16))) float an[4][64];
    __shared__ __attribute__((aligned(16))) float u1[4][64];
    int ty = threadIdx.y, c = threadIdx.x;
    int n = blockIdx.x * 4 + ty;   // NN divisible by 4: always valid
    const float* W0 = wblk + OFF_NW0 + l * 8192;
    const float* b0 = wblk + OFF_NB0 + l * 64;
    const float* W1 = wblk + OFF_NW1 + l * 4096;
    const float* b1 = wblk + OFF_NB1 + l * 64;
    float hv = h[(size_t)n * 64 + c];
    float av = agg[(size_t)n * 64 + c];
    hn[ty][c] = hv; an[ty][c] = av;
    __syncthreads();
    float a = b0[c];
#pragma unroll
    for (int k = 0; k < 64; ++k)
        a += hn[ty][k] * W0[k * 64 + c] + an[ty][k] * W0[(64 + k) * 64 + c];
    u1[ty][c] = eluf(a);
    __syncthreads();
    float a2 = b1[c];
#pragma unroll
    for (int k = 0; k < 64; ++k) a2 += u1[ty][k] * W1[k * 64 + c];
    float nh = hv + a2;
    if (!last) {
        h[(size_t)n * 64 + c] = nh;
        h2[(size_t)n * 64 + c] = f2bu(nh);
        return;
    }
    // fused decoder
    const float* dW0 = wblk + OFF_DEC_W0;
    const float* db0 = wblk + OFF_DEC_B0;
    const float* dW1 = wblk + OFF_DEC_W1;
    const float* db1 = wblk + OFF_DEC_B1;
    __syncthreads();
    hn[ty][c] = nh;
    __syncthreads();
    float d = db0[c];
#pragma unroll
    for (int k = 0; k < 64; ++k) d += hn[ty][k] * dW0[k * 64 + c];
    u1[ty][c] = eluf(d);
    __syncthreads();
    if (c < 3) {
        float o = db1[c];
#pragma unroll
        for (int k = 0; k < 64; ++k) o += u1[ty][k] * dW1[k * 3 + c];
        if (flags[0]) ((float*)out)[n * 3 + c] = o;
        else          ((bf16*)out)[n * 3 + c] = __float2bfloat16(o);
    }
}

extern "C" void kernel_launch(void* const* d_in, const int* in_sizes, int n_in,
                              void* d_out, int out_size, void* d_ws, size_t ws_size,
                              hipStream_t stream) {
    // Workspace (f32 words), total ~79.6 MB
    int*   flags = (int*)d_ws;                       // 16
    float* wblk  = (float*)d_ws + 16;                // 83456
    u16*   swz   = (u16*)(wblk + WBLK_WORDS);        // 14336 words
    float* xf    = wblk + WBLK_WORDS + 14336;        // 300000
    float* pf    = xf + 300000;                      // 300000
    float* agg   = pf + 300000;                      // 6.4M
    float* hbuf  = agg + (size_t)6400000;            // 6.4M
    u16*   h2    = (u16*)(hbuf + (size_t)6400000);   // 3.2M words
    int2*  epk   = (int2*)(h2 + (size_t)6400000);    // 3.2M words

    probe_kernel<<<1, 64, 0, stream>>>((const u16*)d_in[0],
                                       (const unsigned int*)d_in[2], flags);

    WPtrs wp;
    wp.p[0] = d_in[3];  wp.p[1] = d_in[4];  wp.p[2] = d_in[5];  wp.p[3] = d_in[6];
    wp.p[4] = d_in[7];  wp.p[5] = d_in[8];  wp.p[6] = d_in[9];  wp.p[7] = d_in[10];
    wp.p[8] = d_in[11]; wp.p[9] = d_in[12]; wp.p[10] = d_in[13]; wp.p[11] = d_in[14];
    wp.p[12] = d_in[15]; wp.p[13] = d_in[16]; wp.p[14] = d_in[17]; wp.p[15] = d_in[18];
    canon_weights<<<dim3(98, 16), 256, 0, stream>>>(wp, wblk, flags);
    canon_xp<<<dim3(1172, 2), 256, 0, stream>>>(d_in[0], d_in[1], xf, pf, flags);
    prep_edges<<<6250, 256, 0, stream>>>(d_in[2], epk, flags);
    prep_cacb<<<32, 256, 0, stream>>>(wblk);
    prep_swz<<<112, 256, 0, stream>>>(wblk, swz);

    dim3 blk(64, 4);
    encoder_kernel<<<25000, blk, 0, stream>>>(xf, wblk, hbuf, h2);

    const int EDGE_BLOCKS = 2048;
    const int NWAVES = EDGE_BLOCKS * 4;
    const int NGROUPS = NE / 16;
    for (int l = 0; l < 2; ++l) {
        zero_agg<<<6250, 256, 0, stream>>>(agg);
        edge_mfma<<<EDGE_BLOCKS, 256, 0, stream>>>(
            h2, pf, epk,
            swz + (size_t)l * 10240, swz + 20480 + (size_t)l * 4096,
            wblk + OFF_EB0 + l * 64, wblk + OFF_EB1 + l * 64,
            agg, NGROUPS, NWAVES);
        node_kernel<<<25000, blk, 0, stream>>>(hbuf, h2, agg, wblk, l, (l == 1),
                                               d_out, flags);
    }
}